// Round 18
// baseline (1208.111 us; speedup 1.0000x reference)
//
#include <hip/hip_runtime.h>
#include <hip/hip_bf16.h>

// EncoderLayer on MI355X (gfx950).  (R17 + attn single-buffer K/V, 8 blocks/CU)
// prep -> QKV GEMM (8-phase 256²) -> flash attn (16KB LDS, 32 waves/CU,
// exact 1.0-round grid) -> proj GEMM (split-K=2) -> LN1 (fused reduce) ->
// FFN1 GEMM (8-phase 256²) -> FFN2 GEMM (split-K=2) -> LN2 (fused reduce).

#define DEV __device__ __forceinline__

using s16x8  = __attribute__((ext_vector_type(8))) short;   // 8 bf16 MFMA frag
using f32x4  = __attribute__((ext_vector_type(4))) float;

DEV unsigned short f2bf(float f) {            // f32 -> bf16 RNE
  unsigned u = __float_as_uint(f);
  u += 0x7fffu + ((u >> 16) & 1u);
  return (unsigned short)(u >> 16);
}
DEV unsigned cvt_pk_bf16(float lo, float hi) {
  unsigned r;
  asm("v_cvt_pk_bf16_f32 %0, %1, %2" : "=v"(r) : "v"(lo), "v"(hi));
  return r;
}
DEV float bf2f(unsigned short b) { return __uint_as_float((unsigned)b << 16); }

typedef __attribute__((address_space(3))) unsigned lds_u32_t;
typedef const __attribute__((address_space(1))) unsigned glb_u32_t;

DEV void gld_lds16(const void* g, void* l) {
  __builtin_amdgcn_global_load_lds((glb_u32_t*)g, (lds_u32_t*)l, 16, 0, 0);
}

// ---------------------------------------------------------------------------
// 8-phase 256x256 GEMM (T2+T3+T4+T5). VOUT=1 (QKV): cols<1024 Q-scaled by
// 0.125*log2e; cols>=2048 V -> transposed to vtout. SPLITK=1 (proj/FFN2):
// 256 blocks = 32M x 4N x 2K-halves; bf16 partials to Cb + kz*M*N.
// ---------------------------------------------------------------------------
template<int RELU, int VOUT, int SPLITK>
__global__ __launch_bounds__(512, 2)
void gemm8p(const unsigned short* __restrict__ A, const unsigned short* __restrict__ Bt,
            unsigned short* __restrict__ Cb, const float* __restrict__ bias,
            unsigned short* __restrict__ vtout, int M, int N, int K)
{
  __shared__ unsigned short Sh[2][2][256 * 64];
  const int tid = threadIdx.x;
  const int w = tid >> 6, lane = tid & 63;
  const int g = lane >> 4, q = lane & 15;
  const int wr = w >> 2, wc = w & 3;

  const int nwg  = gridDim.x * gridDim.y;
  const int flat = blockIdx.y * gridDim.x + blockIdx.x;
  const int rm   = (flat & 7) * (nwg >> 3) + (flat >> 3);
  int m0, n0, kz = 0;
  if (SPLITK) {                               // 32M x 4N x 2K (nwg = 256)
    kz = rm >> 7;
    const int sp = rm & 127;
    m0 = (sp >> 2) * 256; n0 = (sp & 3) * 256;
  } else {
    m0 = (rm / gridDim.x) * 256; n0 = (rm % gridDim.x) * 256;
  }

  f32x4 acc[8][4] = {};

  const int srow = w * 8 + (lane >> 3);
  const int scol = ((lane & 7) ^ (lane >> 3)) * 8;
  const unsigned short* Ag = A  + (size_t)(m0 + srow) * K + scol + (SPLITK ? kz * (K >> 1) : 0);
  const unsigned short* Bg = Bt + (size_t)(n0 + srow) * K + scol + (SPLITK ? kz * (K >> 1) : 0);

  auto STG = [&](const unsigned short* Gb, int buf, int ab, int half, int kt) {
    const unsigned short* gs = Gb + (size_t)(half * 128) * K + kt * 64;
    unsigned short* ls = &Sh[buf][ab][(half * 128 + w * 8) * 64];
    gld_lds16(gs, ls);
    gld_lds16(gs + (size_t)64 * K, ls + 64 * 64);
  };
  auto LDA = [&](int buf, int mq, s16x8 af[4][2]) {
#pragma unroll
    for (int mm = 0; mm < 4; ++mm) {
      const unsigned short* rp = &Sh[buf][0][(wr * 128 + mq * 64 + mm * 16 + q) * 64];
#pragma unroll
      for (int kk = 0; kk < 2; ++kk)
        af[mm][kk] = *(const s16x8*)(rp + (((kk * 4 + g) ^ (q & 7)) * 8));
    }
  };
  auto LDB = [&](int buf, int nq, s16x8 bf[2][2]) {
#pragma unroll
    for (int nn = 0; nn < 2; ++nn) {
      const unsigned short* rp = &Sh[buf][1][(wc * 64 + nq * 32 + nn * 16 + q) * 64];
#pragma unroll
      for (int kk = 0; kk < 2; ++kk)
        bf[nn][kk] = *(const s16x8*)(rp + (((kk * 4 + g) ^ (q & 7)) * 8));
    }
  };
  auto MQ = [&](int mq, int nq, const s16x8 af[4][2], const s16x8 bf[2][2]) {
    __builtin_amdgcn_s_setprio(1);
#pragma unroll
    for (int kk = 0; kk < 2; ++kk)
#pragma unroll
      for (int mm = 0; mm < 4; ++mm)
#pragma unroll
        for (int nn = 0; nn < 2; ++nn)
          acc[mq * 4 + mm][nq * 2 + nn] = __builtin_amdgcn_mfma_f32_16x16x32_bf16(
              af[mm][kk], bf[nn][kk], acc[mq * 4 + mm][nq * 2 + nn], 0, 0, 0);
    __builtin_amdgcn_s_setprio(0);
  };
  auto BAR = [&]() { __builtin_amdgcn_sched_barrier(0); __builtin_amdgcn_s_barrier(); };

  STG(Ag, 0, 0, 0, 0); STG(Ag, 0, 0, 1, 0);
  STG(Bg, 0, 1, 0, 0); STG(Bg, 0, 1, 1, 0);

  const int NKT = SPLITK ? (K >> 7) : (K >> 6);
  s16x8 af[4][2], bf0[2][2], bf1[2][2];
#pragma unroll 1
  for (int kt = 0; kt < NKT; ++kt) {
    const int b = kt & 1, sb = b ^ 1, kn = kt + 1;
    const bool stg = (kn < NKT);
    if (stg) { STG(Ag, sb, 0, 0, kn); asm volatile("s_waitcnt vmcnt(2)" ::: "memory"); }
    else     {                        asm volatile("s_waitcnt vmcnt(0)" ::: "memory"); }
    BAR();
    LDA(b, 0, af); LDB(b, 0, bf0);
    MQ(0, 0, af, bf0);
    BAR();
    if (stg) STG(Ag, sb, 0, 1, kn);
    LDB(b, 1, bf1);
    MQ(0, 1, af, bf1);
    BAR();
    if (stg) STG(Bg, sb, 1, 0, kn);
    LDA(b, 1, af);
    MQ(1, 0, af, bf0);
    BAR();
    if (stg) STG(Bg, sb, 1, 1, kn);
    MQ(1, 1, af, bf1);
    BAR();
  }

#pragma unroll
  for (int n = 0; n < 4; ++n) {
    const int col = n0 + wc * 64 + n * 16 + q;
    if (SPLITK) {                              // bf16 partial, no bias
      unsigned short* Cp = Cb + (size_t)kz * M * N;
#pragma unroll
      for (int m = 0; m < 8; ++m) {
        const int row0 = m0 + wr * 128 + m * 16 + g * 4;
#pragma unroll
        for (int r = 0; r < 4; ++r)
          Cp[(size_t)(row0 + r) * N + col] = f2bf(acc[m][n][r]);
      }
    } else if (VOUT && col >= 2048) {          // V: write transposed
      const int cv = col - 2048;
#pragma unroll
      for (int m = 0; m < 8; ++m) {
        const int row0 = m0 + wr * 128 + m * 16 + g * 4;
        const int bb = row0 >> 11;
        ushort4 pk;
        pk.x = f2bf(acc[m][n][0]); pk.y = f2bf(acc[m][n][1]);
        pk.z = f2bf(acc[m][n][2]); pk.w = f2bf(acc[m][n][3]);
        *(ushort4*)(vtout + ((size_t)bb * 1024 + cv) * 2048 + (row0 & 2047)) = pk;
      }
    } else {
      const float scl = (VOUT && col < 1024) ? 0.18033688011112042f : 1.0f;
      const float bv = bias ? bias[col] : 0.0f;
#pragma unroll
      for (int m = 0; m < 8; ++m) {
        const int row0 = m0 + wr * 128 + m * 16 + g * 4;
#pragma unroll
        for (int r = 0; r < 4; ++r) {
          float v = acc[m][n][r] * scl + bv;
          if (RELU) v = fmaxf(v, 0.0f);
          Cb[(size_t)(row0 + r) * N + col] = f2bf(v);
        }
      }
    }
  }
}

// ---------------------------------------------------------------------------
// Flash attention, single-buffered K/V (16KB LDS) at max occupancy:
// __launch_bounds__(256,8) -> 8 blocks/CU = 32 waves/CU; 2048-block grid =
// exactly 1.0 dispatch round. Per tile: vmcnt(0)+barrier (LDS valid) -> QK ->
// exp/pack -> barrier -> P into K region -> PV -> barrier -> STAGE(t+1).
// Staging latency exposed per block, hidden by 8-way block TLP (K/V L2-hot
// via h-innermost remap). Static-max softmax, mask as in-place MFMA C-init.
// ---------------------------------------------------------------------------
__global__ __launch_bounds__(256, 8)
void attn_kernel(const unsigned short* __restrict__ qkv,   // [8192][3072]
                 const unsigned short* __restrict__ vt,    // [(b*16+h)*64+d][2048]
                 const float* __restrict__ mask,           // [4][2048][2048]
                 unsigned short* __restrict__ outb)        // [8192][1024]
{
  __shared__ unsigned short Ks[4096];
  __shared__ unsigned short Vs[4096];
  const int tid = threadIdx.x, wave = tid >> 6, lane = tid & 63;
  const int g = lane >> 4, q = lane & 15;

  const int flat = blockIdx.y * 32 + blockIdx.x;
  const int rm   = (flat & 7) * 256 + (flat >> 3);
  const int h  = rm & 15;
  const int qt = (rm >> 4) & 31;
  const int b  = rm >> 9;
  const int qrow = qt * 64 + wave * 16;
  const size_t tok0 = (size_t)b * 2048;

  const unsigned short* Qp = qkv + (tok0 + qrow + q) * 3072 + h * 64;
  const s16x8 bq0 = *(const s16x8*)(Qp + g * 8);
  const s16x8 bq1 = *(const s16x8*)(Qp + 32 + g * 8);
  const float* Mp = mask + ((size_t)b * 2048 + qrow + q) * 2048 + g * 4;

  const int lr = lane >> 3;
  const int sc = (lane & 7) ^ lr;
  const unsigned short* Kg = qkv + tok0 * 3072 + 1024 + h * 64
                           + (size_t)(wave * 16 + lr) * 3072 + sc * 8;
  const unsigned short* Vg = vt + (((size_t)b * 16 + h) * 64 + wave * 16 + lr) * 2048 + sc * 8;
  unsigned short* KsW = Ks + wave * 1024;
  unsigned short* VsW = Vs + wave * 1024;

  s16x8 ones;
#pragma unroll
  for (int j = 0; j < 8; ++j) ones[j] = (short)0x3F80;     // bf16 1.0

  f32x4 ot[4] = {};
  f32x4 sacc = {};                           // [0] = softmax denominator
  f32x4 mk0[4], mk1[4];
  const float L2E = 1.4426950408889634f;

  auto STAGE = [&]() {                       // stage CURRENT Kg/Vg tile
    gld_lds16(Kg,            KsW);
    gld_lds16(Kg + 8 * 3072, KsW + 512);
    gld_lds16(Vg,            VsW);
    gld_lds16(Vg + 8 * 2048, VsW + 512);
  };

  STAGE();                                   // tile 0 in flight
#pragma unroll
  for (int m2 = 0; m2 < 4; ++m2) {
    const f32x4 r = *(const f32x4*)(Mp + m2 * 16);
#pragma unroll
    for (int i = 0; i < 4; ++i) mk0[m2][i] = fmaf(r[i], L2E, -8.0f);
  }

#define ATTN_TILE(MKC, MKN, STG)                                               \
  {                                                                            \
    f32x4 mu[4];                                                               \
    asm volatile("s_waitcnt vmcnt(0)" ::: "memory");  /* own staging done */   \
    __builtin_amdgcn_s_barrier();            /* all waves' staging visible */  \
    if (STG) {                               /* prefetch next-tile mask */     \
      Mp += 64;                                                                \
      mu[0] = *(const f32x4*)(Mp);      mu[1] = *(const f32x4*)(Mp + 16);      \
      mu[2] = *(const f32x4*)(Mp + 32); mu[3] = *(const f32x4*)(Mp + 48);      \
    }                                                                          \
    __builtin_amdgcn_s_setprio(1);                                             \
    _Pragma("unroll")                                                          \
    for (int m2 = 0; m2 < 4; ++m2) {                                           \
      const unsigned short* kp = Ks + (m2 * 16 + q) * 64;                      \
      const s16x8 ak0 = *(const s16x8*)(kp + ((g       ^ (q & 7)) * 8));       \
      const s16x8 ak1 = *(const s16x8*)(kp + (((g + 4) ^ (q & 7)) * 8));       \
      MKC[m2] = __builtin_amdgcn_mfma_f32_16x16x32_bf16(ak0, bq0, MKC[m2], 0, 0, 0); \
      MKC[m2] = __builtin_amdgcn_mfma_f32_16x16x32_bf16(ak1, bq1, MKC[m2], 0, 0, 0); \
    }                                                                          \
    __builtin_amdgcn_s_setprio(0);                                             \
    uint2 pkk[4];                                                              \
    _Pragma("unroll")                                                          \
    for (int m2 = 0; m2 < 4; ++m2) {                                           \
      MKC[m2][0] = exp2f(MKC[m2][0]); MKC[m2][1] = exp2f(MKC[m2][1]);          \
      MKC[m2][2] = exp2f(MKC[m2][2]); MKC[m2][3] = exp2f(MKC[m2][3]);          \
      pkk[m2].x = cvt_pk_bf16(MKC[m2][0], MKC[m2][1]);                         \
      pkk[m2].y = cvt_pk_bf16(MKC[m2][2], MKC[m2][3]);                         \
    }                                                                          \
    __builtin_amdgcn_sched_barrier(0);                                         \
    __builtin_amdgcn_s_barrier();            /* all waves done reading K */    \
    char* Pw = (char*)Ks + wave * 2048;                                        \
    _Pragma("unroll")                                                          \
    for (int m2 = 0; m2 < 4; ++m2) {                                           \
      const int bir  = m2 * 32 + g * 8;                                        \
      const int addr = q * 128 + (((bir >> 4) ^ (q & 7)) << 4) + (bir & 15);   \
      *(uint2*)(Pw + addr) = pkk[m2];                                          \
    }                                                                          \
    __builtin_amdgcn_s_setprio(1);                                             \
    _Pragma("unroll")                                                          \
    for (int kb = 0; kb < 2; ++kb) {                                           \
      const int blk = (kb * 4 + g) ^ (q & 7);                                  \
      const s16x8 pb = *(const s16x8*)(Pw + q * 128 + blk * 16);               \
      sacc = __builtin_amdgcn_mfma_f32_16x16x32_bf16(ones, pb, sacc, 0, 0, 0); \
      _Pragma("unroll")                                                        \
      for (int mm = 0; mm < 4; ++mm) {                                         \
        const s16x8 av = *(const s16x8*)(Vs + (mm * 16 + q) * 64 + blk * 8);   \
        ot[mm] = __builtin_amdgcn_mfma_f32_16x16x32_bf16(av, pb, ot[mm], 0, 0, 0); \
      }                                                                        \
    }                                                                          \
    __builtin_amdgcn_s_setprio(0);                                             \
    if (STG) {                               /* transform next-tile mask */    \
      _Pragma("unroll")                                                        \
      for (int m2 = 0; m2 < 4; ++m2) {                                         \
        MKN[m2][0] = fmaf(mu[m2][0], L2E, -8.0f);                              \
        MKN[m2][1] = fmaf(mu[m2][1], L2E, -8.0f);                              \
        MKN[m2][2] = fmaf(mu[m2][2], L2E, -8.0f);                              \
        MKN[m2][3] = fmaf(mu[m2][3], L2E, -8.0f);                              \
      }                                                                        \
    }                                                                          \
    __builtin_amdgcn_sched_barrier(0);                                         \
    __builtin_amdgcn_s_barrier();            /* all waves done with V and P */ \
    if (STG) { Kg += 64 * 3072; Vg += 64; STAGE(); }  /* overwrite for t+1 */  \
  }

#pragma unroll 1
  for (int tt = 0; tt < 16; ++tt) {
    ATTN_TILE(mk0, mk1, true);               // tiles 0,2,..,30
    ATTN_TILE(mk1, mk0, (tt < 15));          // tiles 1,3,..,31
  }
#undef ATTN_TILE

  // epilogue: O-transpose through own wave region of Ks (last barrier passed)
  char* Pw0 = (char*)Ks + wave * 2048;
  const float inv = 1.0f / sacc[0];
#pragma unroll
  for (int mm = 0; mm < 4; ++mm) {
    const int bir  = mm * 32 + g * 8;
    const int addr = q * 128 + (((bir >> 4) ^ (q & 7)) << 4) + (bir & 15);
    uint2 pk;
    pk.x = cvt_pk_bf16(ot[mm][0] * inv, ot[mm][1] * inv);
    pk.y = cvt_pk_bf16(ot[mm][2] * inv, ot[mm][3] * inv);
    *(uint2*)(Pw0 + addr) = pk;
  }
#pragma unroll
  for (int p = 0; p < 2; ++p) {
    const int c  = p * 64 + lane;
    const int qq = c >> 3, cc = c & 7;
    const int blk = cc ^ (qq & 7);
    const s16x8 vv = *(const s16x8*)(Pw0 + qq * 128 + blk * 16);
    *(s16x8*)(outb + (tok0 + qrow + qq) * 1024 + h * 64 + cc * 8) = vv;
  }
}

// ---------------------------------------------------------------------------
// Row LayerNorm over D=1024 with fused split-K reduce:
// v = bf16(p0) + bf16(p1) + bias + bf16-resid.
// ---------------------------------------------------------------------------
__global__ __launch_bounds__(256)
void ln_kernel(const unsigned short* __restrict__ p0, const unsigned short* __restrict__ p1,
               const float* __restrict__ bias, const unsigned short* __restrict__ residb,
               float* __restrict__ outf, unsigned short* __restrict__ outb,
               const float* __restrict__ gam, const float* __restrict__ bet)
{
  __shared__ float red[8];
  const int row = blockIdx.x, tid = threadIdx.x;
  const size_t base = (size_t)row * 1024 + tid * 4;
  const uint2 a = *(const uint2*)(p0 + base);
  const uint2 c = *(const uint2*)(p1 + base);
  const f32x4 bs = *(const f32x4*)(bias + tid * 4);
  const uint2 u = *(const uint2*)(residb + base);
  f32x4 v;
  v[0] = __uint_as_float(a.x << 16)         + __uint_as_float(c.x << 16)
       + bs[0] + __uint_as_float(u.x << 16);
  v[1] = __uint_as_float(a.x & 0xffff0000u) + __uint_as_float(c.x & 0xffff0000u)
       + bs[1] + __uint_as_float(u.x & 0xffff0000u);
  v[2] = __uint_as_float(a.y << 16)         + __uint_as_float(c.y << 16)
       + bs[2] + __uint_as_float(u.y << 16);
  v[3] = __uint_as_float(a.y & 0xffff0000u) + __uint_as_float(c.y & 0xffff0000u)
       + bs[3] + __uint_as_float(u.y & 0xffff0000u);
  float s  = v[0] + v[1] + v[2] + v[3];
  float ss = v[0]*v[0] + v[1]*v[1] + v[2]*v[2] + v[3]*v[3];
#pragma unroll
  for (int o = 1; o < 64; o <<= 1) { s += __shfl_xor(s, o); ss += __shfl_xor(ss, o); }
  if ((tid & 63) == 0) { red[tid >> 6] = s; red[4 + (tid >> 6)] = ss; }
  __syncthreads();
  s  = red[0] + red[1] + red[2] + red[3];
  ss = red[4] + red[5] + red[6] + red[7];
  const float mean = s * (1.0f / 1024.0f);
  const float var  = ss * (1.0f / 1024.0f) - mean * mean;
  const float rstd = rsqrtf(var + 1e-5f);
  const f32x4 gm = *(const f32x4*)(gam + tid * 4);
  const f32x4 bt = *(const f32x4*)(bet + tid * 4);
  f32x4 o;
#pragma unroll
  for (int j = 0; j < 4; ++j) o[j] = (v[j] - mean) * rstd * gm[j] + bt[j];
  if (outf) *(f32x4*)(outf + base) = o;
  if (outb) {
    uint2 pk; pk.x = cvt_pk_bf16(o[0], o[1]); pk.y = cvt_pk_bf16(o[2], o[3]);
    *(uint2*)(outb + base) = pk;
  }
}

// ---------------------------------------------------------------------------
// Fused prep: blocks [0,8192) cast x f32->bf16; blocks [8192,16384) transpose-
// cast the 6 weight matrices.
// ---------------------------------------------------------------------------
__global__ __launch_bounds__(256)
void prep_kernel(const float* __restrict__ x, unsigned short* __restrict__ xb,
                 const float* __restrict__ Wq, const float* __restrict__ Wk,
                 const float* __restrict__ Wv, const float* __restrict__ Wc,
                 const float* __restrict__ W1, const float* __restrict__ W2,
                 unsigned short* __restrict__ wqkvt, unsigned short* __restrict__ wct,
                 unsigned short* __restrict__ w1t, unsigned short* __restrict__ w2t)
{
  const int bid = blockIdx.x;
  if (bid < 8192) {                          // cast x
    const size_t i = ((size_t)bid * 256 + threadIdx.x) * 4;
    const f32x4 v = *(const f32x4*)(x + i);
    uint2 pk; pk.x = cvt_pk_bf16(v[0], v[1]); pk.y = cvt_pk_bf16(v[2], v[3]);
    *(uint2*)(xb + i) = pk;
    return;
  }
  __shared__ float t[32][33];
  const int t2 = bid - 8192;
  const float* in; unsigned short* out; int R, C, bx, by;
  if (t2 < 4096) {                           // Wq/Wk/Wv/Wc [1024][1024]
    const int widx = t2 >> 10, sub = t2 & 1023;
    in  = (widx == 0) ? Wq : (widx == 1) ? Wk : (widx == 2) ? Wv : Wc;
    out = (widx < 3) ? (wqkvt + (size_t)widx * 1024 * 1024) : wct;
    R = 1024; C = 1024; bx = sub & 31; by = sub >> 5;
  } else if (t2 < 6144) {                    // W1 [1024][2048]
    const int sub = t2 - 4096;
    in = W1; out = w1t; R = 1024; C = 2048; bx = sub & 63; by = sub >> 6;
  } else {                                   // W2 [2048][1024]
    const int sub = t2 - 6144;
    in = W2; out = w2t; R = 2048; C = 1024; bx = sub & 31; by = sub >> 5;
  }
  const int tx = threadIdx.x & 31, ty = threadIdx.x >> 5;
  const int c0 = bx * 32, r0 = by * 32;
#pragma unroll
  for (int k = 0; k < 4; ++k)
    t[ty + k * 8][tx] = in[(size_t)(r0 + ty + k * 8) * C + c0 + tx];
  __syncthreads();
#pragma unroll
  for (int k = 0; k < 4; ++k)
    out[(size_t)(c0 + ty + k * 8) * R + r0 + tx] = f2bf(t[tx][ty + k * 8]);
}

extern "C" void kernel_launch(void* const* d_in, const int* in_sizes, int n_in,
                              void* d_out, int out_size, void* d_ws, size_t ws_size,
                              hipStream_t stream)
{
  (void)in_sizes; (void)n_in; (void)out_size; (void)ws_size;  // needs ws_size >= 144MB
  const float* x   = (const float*)d_in[0];
  const float* msk = (const float*)d_in[1];
  const float* Wq  = (const float*)d_in[2];
  const float* Wk  = (const float*)d_in[3];
  const float* Wv  = (const float*)d_in[4];
  const float* Wc  = (const float*)d_in[5];
  const float* bc  = (const float*)d_in[6];
  const float* W1  = (const float*)d_in[7];
  const float* b1  = (const float*)d_in[8];
  const float* W2  = (const float*)d_in[9];
  const float* b2  = (const float*)d_in[10];
  const float* g1  = (const float*)d_in[11];
  const float* be1 = (const float*)d_in[12];
  const float* g2  = (const float*)d_in[13];
  const float* be2 = (const float*)d_in[14];
  float* out = (float*)d_out;
  char* ws = (char*)d_ws;
  const size_t MB = 1u << 20;
  unsigned short* xb    = (unsigned short*)(ws + 0 * MB);    // bf16 x, live to LN1
  unsigned short* wqkvt = (unsigned short*)(ws + 16 * MB);
  unsigned short* wct   = (unsigned short*)(ws + 22 * MB);
  unsigned short* w1t   = (unsigned short*)(ws + 24 * MB);
  unsigned short* w2t   = (unsigned short*)(ws + 28 * MB);
  unsigned short* qkv   = (unsigned short*)(ws + 32 * MB);   // 48MB, dead after attn
  unsigned short* vt    = (unsigned short*)(ws + 80 * MB);   // 16MB, dead after attn
  unsigned short* attnb = (unsigned short*)(ws + 96 * MB);   // 16MB, dead after proj
  unsigned short* h1b   = (unsigned short*)(ws + 128 * MB);  // 16MB, live to LN2
  unsigned short* prb   = (unsigned short*)(ws + 32 * MB);   // 32MB proj partials
  unsigned short* midb  = (unsigned short*)(ws + 32 * MB);   // 32MB FFN1 out (after LN1)
  unsigned short* pffb  = (unsigned short*)(ws + 64 * MB);   // 32MB FFN2 partials

  prep_kernel<<<16384, 256, 0, stream>>>(x, xb, Wq, Wk, Wv, Wc, W1, W2,
                                         wqkvt, wct, w1t, w2t);
  gemm8p<0, 1, 0><<<dim3(12, 32), 512, 0, stream>>>(xb, wqkvt, qkv, nullptr, vt,
                                                    8192, 3072, 1024);
  attn_kernel<<<dim3(32, 64), 256, 0, stream>>>(qkv, vt, msk, attnb);
  gemm8p<0, 0, 1><<<dim3(8, 32), 512, 0, stream>>>(attnb, wct, prb, nullptr, nullptr,
                                                   8192, 1024, 1024);
  ln_kernel<<<8192, 256, 0, stream>>>(prb, prb + (size_t)8192 * 1024,
                                      bc, xb, nullptr, h1b, g1, be1);
  gemm8p<1, 0, 0><<<dim3(8, 32), 512, 0, stream>>>(h1b, w1t, midb, b1, nullptr,
                                                   8192, 2048, 1024);
  gemm8p<0, 0, 1><<<dim3(8, 32), 512, 0, stream>>>(midb, w2t, pffb, nullptr, nullptr,
                                                   8192, 1024, 2048);
  ln_kernel<<<8192, 256, 0, stream>>>(pffb, pffb + (size_t)8192 * 1024,
                                      b2, h1b, out, nullptr, g2, be2);
}

// Round 19
// 392.468 us; speedup vs baseline: 3.0782x; 3.0782x over previous
//
#include <hip/hip_runtime.h>
#include <hip/hip_bf16.h>

// EncoderLayer on MI355X (gfx950).  (R17 configuration — session best, final)
// prep -> QKV GEMM (8-phase 256²) -> flash attn (P-in-K-buffer, 32KB LDS,
// 4 blocks/CU) -> proj GEMM (split-K=2, bf16 partials) -> LN1 (reduce +bc +xb)
// -> FFN1 GEMM (8-phase 256²) -> FFN2 GEMM (split-K=2) -> LN2 (reduce +b2 +h1b).

#define DEV __device__ __forceinline__

using s16x8  = __attribute__((ext_vector_type(8))) short;   // 8 bf16 MFMA frag
using f32x4  = __attribute__((ext_vector_type(4))) float;

DEV unsigned short f2bf(float f) {            // f32 -> bf16 RNE
  unsigned u = __float_as_uint(f);
  u += 0x7fffu + ((u >> 16) & 1u);
  return (unsigned short)(u >> 16);
}
DEV unsigned cvt_pk_bf16(float lo, float hi) {
  unsigned r;
  asm("v_cvt_pk_bf16_f32 %0, %1, %2" : "=v"(r) : "v"(lo), "v"(hi));
  return r;
}
DEV float bf2f(unsigned short b) { return __uint_as_float((unsigned)b << 16); }

typedef __attribute__((address_space(3))) unsigned lds_u32_t;
typedef const __attribute__((address_space(1))) unsigned glb_u32_t;

DEV void gld_lds16(const void* g, void* l) {
  __builtin_amdgcn_global_load_lds((glb_u32_t*)g, (lds_u32_t*)l, 16, 0, 0);
}

// ---------------------------------------------------------------------------
// 8-phase 256x256 GEMM (T2+T3+T4+T5). VOUT=1 (QKV): cols<1024 Q-scaled by
// 0.125*log2e; cols>=2048 V -> transposed to vtout. SPLITK=1 (proj/FFN2):
// 256 blocks = 32M x 4N x 2K-halves; bf16 partials to Cb + kz*M*N.
// ---------------------------------------------------------------------------
template<int RELU, int VOUT, int SPLITK>
__global__ __launch_bounds__(512, 2)
void gemm8p(const unsigned short* __restrict__ A, const unsigned short* __restrict__ Bt,
            unsigned short* __restrict__ Cb, const float* __restrict__ bias,
            unsigned short* __restrict__ vtout, int M, int N, int K)
{
  __shared__ unsigned short Sh[2][2][256 * 64];
  const int tid = threadIdx.x;
  const int w = tid >> 6, lane = tid & 63;
  const int g = lane >> 4, q = lane & 15;
  const int wr = w >> 2, wc = w & 3;

  const int nwg  = gridDim.x * gridDim.y;
  const int flat = blockIdx.y * gridDim.x + blockIdx.x;
  const int rm   = (flat & 7) * (nwg >> 3) + (flat >> 3);
  int m0, n0, kz = 0;
  if (SPLITK) {                               // 32M x 4N x 2K (nwg = 256)
    kz = rm >> 7;
    const int sp = rm & 127;
    m0 = (sp >> 2) * 256; n0 = (sp & 3) * 256;
  } else {
    m0 = (rm / gridDim.x) * 256; n0 = (rm % gridDim.x) * 256;
  }

  f32x4 acc[8][4] = {};

  const int srow = w * 8 + (lane >> 3);
  const int scol = ((lane & 7) ^ (lane >> 3)) * 8;
  const unsigned short* Ag = A  + (size_t)(m0 + srow) * K + scol + (SPLITK ? kz * (K >> 1) : 0);
  const unsigned short* Bg = Bt + (size_t)(n0 + srow) * K + scol + (SPLITK ? kz * (K >> 1) : 0);

  auto STG = [&](const unsigned short* Gb, int buf, int ab, int half, int kt) {
    const unsigned short* gs = Gb + (size_t)(half * 128) * K + kt * 64;
    unsigned short* ls = &Sh[buf][ab][(half * 128 + w * 8) * 64];
    gld_lds16(gs, ls);
    gld_lds16(gs + (size_t)64 * K, ls + 64 * 64);
  };
  auto LDA = [&](int buf, int mq, s16x8 af[4][2]) {
#pragma unroll
    for (int mm = 0; mm < 4; ++mm) {
      const unsigned short* rp = &Sh[buf][0][(wr * 128 + mq * 64 + mm * 16 + q) * 64];
#pragma unroll
      for (int kk = 0; kk < 2; ++kk)
        af[mm][kk] = *(const s16x8*)(rp + (((kk * 4 + g) ^ (q & 7)) * 8));
    }
  };
  auto LDB = [&](int buf, int nq, s16x8 bf[2][2]) {
#pragma unroll
    for (int nn = 0; nn < 2; ++nn) {
      const unsigned short* rp = &Sh[buf][1][(wc * 64 + nq * 32 + nn * 16 + q) * 64];
#pragma unroll
      for (int kk = 0; kk < 2; ++kk)
        bf[nn][kk] = *(const s16x8*)(rp + (((kk * 4 + g) ^ (q & 7)) * 8));
    }
  };
  auto MQ = [&](int mq, int nq, const s16x8 af[4][2], const s16x8 bf[2][2]) {
    __builtin_amdgcn_s_setprio(1);
#pragma unroll
    for (int kk = 0; kk < 2; ++kk)
#pragma unroll
      for (int mm = 0; mm < 4; ++mm)
#pragma unroll
        for (int nn = 0; nn < 2; ++nn)
          acc[mq * 4 + mm][nq * 2 + nn] = __builtin_amdgcn_mfma_f32_16x16x32_bf16(
              af[mm][kk], bf[nn][kk], acc[mq * 4 + mm][nq * 2 + nn], 0, 0, 0);
    __builtin_amdgcn_s_setprio(0);
  };
  auto BAR = [&]() { __builtin_amdgcn_sched_barrier(0); __builtin_amdgcn_s_barrier(); };

  STG(Ag, 0, 0, 0, 0); STG(Ag, 0, 0, 1, 0);
  STG(Bg, 0, 1, 0, 0); STG(Bg, 0, 1, 1, 0);

  const int NKT = SPLITK ? (K >> 7) : (K >> 6);
  s16x8 af[4][2], bf0[2][2], bf1[2][2];
#pragma unroll 1
  for (int kt = 0; kt < NKT; ++kt) {
    const int b = kt & 1, sb = b ^ 1, kn = kt + 1;
    const bool stg = (kn < NKT);
    if (stg) { STG(Ag, sb, 0, 0, kn); asm volatile("s_waitcnt vmcnt(2)" ::: "memory"); }
    else     {                        asm volatile("s_waitcnt vmcnt(0)" ::: "memory"); }
    BAR();
    LDA(b, 0, af); LDB(b, 0, bf0);
    MQ(0, 0, af, bf0);
    BAR();
    if (stg) STG(Ag, sb, 0, 1, kn);
    LDB(b, 1, bf1);
    MQ(0, 1, af, bf1);
    BAR();
    if (stg) STG(Bg, sb, 1, 0, kn);
    LDA(b, 1, af);
    MQ(1, 0, af, bf0);
    BAR();
    if (stg) STG(Bg, sb, 1, 1, kn);
    MQ(1, 1, af, bf1);
    BAR();
  }

#pragma unroll
  for (int n = 0; n < 4; ++n) {
    const int col = n0 + wc * 64 + n * 16 + q;
    if (SPLITK) {                              // bf16 partial, no bias
      unsigned short* Cp = Cb + (size_t)kz * M * N;
#pragma unroll
      for (int m = 0; m < 8; ++m) {
        const int row0 = m0 + wr * 128 + m * 16 + g * 4;
#pragma unroll
        for (int r = 0; r < 4; ++r)
          Cp[(size_t)(row0 + r) * N + col] = f2bf(acc[m][n][r]);
      }
    } else if (VOUT && col >= 2048) {          // V: write transposed
      const int cv = col - 2048;
#pragma unroll
      for (int m = 0; m < 8; ++m) {
        const int row0 = m0 + wr * 128 + m * 16 + g * 4;
        const int bb = row0 >> 11;
        ushort4 pk;
        pk.x = f2bf(acc[m][n][0]); pk.y = f2bf(acc[m][n][1]);
        pk.z = f2bf(acc[m][n][2]); pk.w = f2bf(acc[m][n][3]);
        *(ushort4*)(vtout + ((size_t)bb * 1024 + cv) * 2048 + (row0 & 2047)) = pk;
      }
    } else {
      const float scl = (VOUT && col < 1024) ? 0.18033688011112042f : 1.0f;
      const float bv = bias ? bias[col] : 0.0f;
#pragma unroll
      for (int m = 0; m < 8; ++m) {
        const int row0 = m0 + wr * 128 + m * 16 + g * 4;
#pragma unroll
        for (int r = 0; r < 4; ++r) {
          float v = acc[m][n][r] * scl + bv;
          if (RELU) v = fmaxf(v, 0.0f);
          Cb[(size_t)(row0 + r) * N + col] = f2bf(v);
        }
      }
    }
  }
}

// ---------------------------------------------------------------------------
// Flash attention (R15/R17 kernel, verbatim — measured 195us). 16 q-rows/wave,
// 2048 blocks, static-max softmax, unrolled x2, mask as in-place MFMA C-init,
// h-innermost XCD remap, P in current K buffer (32KB LDS, 4 blocks/CU).
// ---------------------------------------------------------------------------
__global__ __launch_bounds__(256, 4)
void attn_kernel(const unsigned short* __restrict__ qkv,   // [8192][3072]
                 const unsigned short* __restrict__ vt,    // [(b*16+h)*64+d][2048]
                 const float* __restrict__ mask,           // [4][2048][2048]
                 unsigned short* __restrict__ outb)        // [8192][1024]
{
  __shared__ unsigned short Ks[2][4096];
  __shared__ unsigned short Vs[2][4096];
  const int tid = threadIdx.x, wave = tid >> 6, lane = tid & 63;
  const int g = lane >> 4, q = lane & 15;

  const int flat = blockIdx.y * 32 + blockIdx.x;
  const int rm   = (flat & 7) * 256 + (flat >> 3);
  const int h  = rm & 15;
  const int qt = (rm >> 4) & 31;
  const int b  = rm >> 9;
  const int qrow = qt * 64 + wave * 16;
  const size_t tok0 = (size_t)b * 2048;

  const unsigned short* Qp = qkv + (tok0 + qrow + q) * 3072 + h * 64;
  const s16x8 bq0 = *(const s16x8*)(Qp + g * 8);
  const s16x8 bq1 = *(const s16x8*)(Qp + 32 + g * 8);
  const float* Mp = mask + ((size_t)b * 2048 + qrow + q) * 2048 + g * 4;

  const int lr = lane >> 3;
  const int sc = (lane & 7) ^ lr;
  const unsigned short* Kg = qkv + tok0 * 3072 + 1024 + h * 64
                           + (size_t)(wave * 16 + lr) * 3072 + sc * 8;
  const unsigned short* Vg = vt + (((size_t)b * 16 + h) * 64 + wave * 16 + lr) * 2048 + sc * 8;
  unsigned short* KsW = Ks[0] + wave * 1024;
  unsigned short* VsW = Vs[0] + wave * 1024;

  s16x8 ones;
#pragma unroll
  for (int j = 0; j < 8; ++j) ones[j] = (short)0x3F80;     // bf16 1.0

  f32x4 ot[4] = {};
  f32x4 sacc = {};                           // [0] = softmax denominator
  f32x4 mk0[4], mk1[4];
  const float L2E = 1.4426950408889634f;

  gld_lds16(Kg,            KsW);
  gld_lds16(Kg + 8 * 3072, KsW + 512);
  gld_lds16(Vg,            VsW);
  gld_lds16(Vg + 8 * 2048, VsW + 512);
#pragma unroll
  for (int m2 = 0; m2 < 4; ++m2) {
    const f32x4 r = *(const f32x4*)(Mp + m2 * 16);
#pragma unroll
    for (int i = 0; i < 4; ++i) mk0[m2][i] = fmaf(r[i], L2E, -8.0f);
  }
  __syncthreads();

#define ATTN_TILE(BUF, MKC, MKN, STG)                                          \
  {                                                                            \
    f32x4 mu[4];                                                               \
    if (STG) {                                                                 \
      Kg += 64 * 3072; Vg += 64; Mp += 64;                                     \
      gld_lds16(Kg,            KsW + (BUF ^ 1) * 4096);                        \
      gld_lds16(Kg + 8 * 3072, KsW + (BUF ^ 1) * 4096 + 512);                  \
      gld_lds16(Vg,            VsW + (BUF ^ 1) * 4096);                        \
      gld_lds16(Vg + 8 * 2048, VsW + (BUF ^ 1) * 4096 + 512);                  \
      mu[0] = *(const f32x4*)(Mp);      mu[1] = *(const f32x4*)(Mp + 16);      \
      mu[2] = *(const f32x4*)(Mp + 32); mu[3] = *(const f32x4*)(Mp + 48);      \
    }                                                                          \
    __builtin_amdgcn_s_setprio(1);                                             \
    _Pragma("unroll")                                                          \
    for (int m2 = 0; m2 < 4; ++m2) {                                           \
      const unsigned short* kp = Ks[BUF] + (m2 * 16 + q) * 64;                 \
      const s16x8 ak0 = *(const s16x8*)(kp + ((g       ^ (q & 7)) * 8));       \
      const s16x8 ak1 = *(const s16x8*)(kp + (((g + 4) ^ (q & 7)) * 8));       \
      MKC[m2] = __builtin_amdgcn_mfma_f32_16x16x32_bf16(ak0, bq0, MKC[m2], 0, 0, 0); \
      MKC[m2] = __builtin_amdgcn_mfma_f32_16x16x32_bf16(ak1, bq1, MKC[m2], 0, 0, 0); \
    }                                                                          \
    __builtin_amdgcn_s_setprio(0);                                             \
    uint2 pkk[4];                                                              \
    _Pragma("unroll")                                                          \
    for (int m2 = 0; m2 < 4; ++m2) {                                           \
      MKC[m2][0] = exp2f(MKC[m2][0]); MKC[m2][1] = exp2f(MKC[m2][1]);          \
      MKC[m2][2] = exp2f(MKC[m2][2]); MKC[m2][3] = exp2f(MKC[m2][3]);          \
      pkk[m2].x = cvt_pk_bf16(MKC[m2][0], MKC[m2][1]);                         \
      pkk[m2].y = cvt_pk_bf16(MKC[m2][2], MKC[m2][3]);                         \
    }                                                                          \
    __builtin_amdgcn_sched_barrier(0);                                         \
    __builtin_amdgcn_s_barrier();   /* all waves done reading K(BUF) */        \
    char* Pw = (char*)(&Ks[BUF][0]) + wave * 2048;                             \
    _Pragma("unroll")                                                          \
    for (int m2 = 0; m2 < 4; ++m2) {                                           \
      const int bir  = m2 * 32 + g * 8;                                        \
      const int addr = q * 128 + (((bir >> 4) ^ (q & 7)) << 4) + (bir & 15);   \
      *(uint2*)(Pw + addr) = pkk[m2];                                          \
    }                                                                          \
    __builtin_amdgcn_s_setprio(1);                                             \
    _Pragma("unroll")                                                          \
    for (int kb = 0; kb < 2; ++kb) {                                           \
      const int blk = (kb * 4 + g) ^ (q & 7);                                  \
      const s16x8 pb = *(const s16x8*)(Pw + q * 128 + blk * 16);               \
      sacc = __builtin_amdgcn_mfma_f32_16x16x32_bf16(ones, pb, sacc, 0, 0, 0); \
      _Pragma("unroll")                                                        \
      for (int mm = 0; mm < 4; ++mm) {                                         \
        const s16x8 av = *(const s16x8*)(Vs[BUF] + (mm * 16 + q) * 64 + blk * 8); \
        ot[mm] = __builtin_amdgcn_mfma_f32_16x16x32_bf16(av, pb, ot[mm], 0, 0, 0); \
      }                                                                        \
    }                                                                          \
    __builtin_amdgcn_s_setprio(0);                                             \
    if (STG) {                                                                 \
      _Pragma("unroll")                                                        \
      for (int m2 = 0; m2 < 4; ++m2) {                                         \
        MKN[m2][0] = fmaf(mu[m2][0], L2E, -8.0f);                              \
        MKN[m2][1] = fmaf(mu[m2][1], L2E, -8.0f);                              \
        MKN[m2][2] = fmaf(mu[m2][2], L2E, -8.0f);                              \
        MKN[m2][3] = fmaf(mu[m2][3], L2E, -8.0f);                              \
      }                                                                        \
    }                                                                          \
    __syncthreads();                                                           \
  }

#pragma unroll 1
  for (int tt = 0; tt < 16; ++tt) {
    ATTN_TILE(0, mk0, mk1, true);            // tiles 0,2,..,30
    ATTN_TILE(1, mk1, mk0, (tt < 15));       // tiles 1,3,..,31
  }
#undef ATTN_TILE

  // epilogue: O-transpose through Ks[0] (dead; all staging complete)
  char* Pw0 = (char*)(&Ks[0][0]) + wave * 2048;
  const float inv = 1.0f / sacc[0];
#pragma unroll
  for (int mm = 0; mm < 4; ++mm) {
    const int bir  = mm * 32 + g * 8;
    const int addr = q * 128 + (((bir >> 4) ^ (q & 7)) << 4) + (bir & 15);
    uint2 pk;
    pk.x = cvt_pk_bf16(ot[mm][0] * inv, ot[mm][1] * inv);
    pk.y = cvt_pk_bf16(ot[mm][2] * inv, ot[mm][3] * inv);
    *(uint2*)(Pw0 + addr) = pk;
  }
#pragma unroll
  for (int p = 0; p < 2; ++p) {
    const int c  = p * 64 + lane;
    const int qq = c >> 3, cc = c & 7;
    const int blk = cc ^ (qq & 7);
    const s16x8 vv = *(const s16x8*)(Pw0 + qq * 128 + blk * 16);
    *(s16x8*)(outb + (tok0 + qrow + qq) * 1024 + h * 64 + cc * 8) = vv;
  }
}

// ---------------------------------------------------------------------------
// Row LayerNorm over D=1024 with fused split-K reduce:
// v = bf16(p0) + bf16(p1) + bias + bf16-resid.
// ---------------------------------------------------------------------------
__global__ __launch_bounds__(256)
void ln_kernel(const unsigned short* __restrict__ p0, const unsigned short* __restrict__ p1,
               const float* __restrict__ bias, const unsigned short* __restrict__ residb,
               float* __restrict__ outf, unsigned short* __restrict__ outb,
               const float* __restrict__ gam, const float* __restrict__ bet)
{
  __shared__ float red[8];
  const int row = blockIdx.x, tid = threadIdx.x;
  const size_t base = (size_t)row * 1024 + tid * 4;
  const uint2 a = *(const uint2*)(p0 + base);
  const uint2 c = *(const uint2*)(p1 + base);
  const f32x4 bs = *(const f32x4*)(bias + tid * 4);
  const uint2 u = *(const uint2*)(residb + base);
  f32x4 v;
  v[0] = __uint_as_float(a.x << 16)         + __uint_as_float(c.x << 16)
       + bs[0] + __uint_as_float(u.x << 16);
  v[1] = __uint_as_float(a.x & 0xffff0000u) + __uint_as_float(c.x & 0xffff0000u)
       + bs[1] + __uint_as_float(u.x & 0xffff0000u);
  v[2] = __uint_as_float(a.y << 16)         + __uint_as_float(c.y << 16)
       + bs[2] + __uint_as_float(u.y << 16);
  v[3] = __uint_as_float(a.y & 0xffff0000u) + __uint_as_float(c.y & 0xffff0000u)
       + bs[3] + __uint_as_float(u.y & 0xffff0000u);
  float s  = v[0] + v[1] + v[2] + v[3];
  float ss = v[0]*v[0] + v[1]*v[1] + v[2]*v[2] + v[3]*v[3];
#pragma unroll
  for (int o = 1; o < 64; o <<= 1) { s += __shfl_xor(s, o); ss += __shfl_xor(ss, o); }
  if ((tid & 63) == 0) { red[tid >> 6] = s; red[4 + (tid >> 6)] = ss; }
  __syncthreads();
  s  = red[0] + red[1] + red[2] + red[3];
  ss = red[4] + red[5] + red[6] + red[7];
  const float mean = s * (1.0f / 1024.0f);
  const float var  = ss * (1.0f / 1024.0f) - mean * mean;
  const float rstd = rsqrtf(var + 1e-5f);
  const f32x4 gm = *(const f32x4*)(gam + tid * 4);
  const f32x4 bt = *(const f32x4*)(bet + tid * 4);
  f32x4 o;
#pragma unroll
  for (int j = 0; j < 4; ++j) o[j] = (v[j] - mean) * rstd * gm[j] + bt[j];
  if (outf) *(f32x4*)(outf + base) = o;
  if (outb) {
    uint2 pk; pk.x = cvt_pk_bf16(o[0], o[1]); pk.y = cvt_pk_bf16(o[2], o[3]);
    *(uint2*)(outb + base) = pk;
  }
}

// ---------------------------------------------------------------------------
// Fused prep: blocks [0,8192) cast x f32->bf16; blocks [8192,16384) transpose-
// cast the 6 weight matrices.
// ---------------------------------------------------------------------------
__global__ __launch_bounds__(256)
void prep_kernel(const float* __restrict__ x, unsigned short* __restrict__ xb,
                 const float* __restrict__ Wq, const float* __restrict__ Wk,
                 const float* __restrict__ Wv, const float* __restrict__ Wc,
                 const float* __restrict__ W1, const float* __restrict__ W2,
                 unsigned short* __restrict__ wqkvt, unsigned short* __restrict__ wct,
                 unsigned short* __restrict__ w1t, unsigned short* __restrict__ w2t)
{
  const int bid = blockIdx.x;
  if (bid < 8192) {                          // cast x
    const size_t i = ((size_t)bid * 256 + threadIdx.x) * 4;
    const f32x4 v = *(const f32x4*)(x + i);
    uint2 pk; pk.x = cvt_pk_bf16(v[0], v[1]); pk.y = cvt_pk_bf16(v[2], v[3]);
    *(uint2*)(xb + i) = pk;
    return;
  }
  __shared__ float t[32][33];
  const int t2 = bid - 8192;
  const float* in; unsigned short* out; int R, C, bx, by;
  if (t2 < 4096) {                           // Wq/Wk/Wv/Wc [1024][1024]
    const int widx = t2 >> 10, sub = t2 & 1023;
    in  = (widx == 0) ? Wq : (widx == 1) ? Wk : (widx == 2) ? Wv : Wc;
    out = (widx < 3) ? (wqkvt + (size_t)widx * 1024 * 1024) : wct;
    R = 1024; C = 1024; bx = sub & 31; by = sub >> 5;
  } else if (t2 < 6144) {                    // W1 [1024][2048]
    const int sub = t2 - 4096;
    in = W1; out = w1t; R = 1024; C = 2048; bx = sub & 63; by = sub >> 6;
  } else {                                   // W2 [2048][1024]
    const int sub = t2 - 6144;
    in = W2; out = w2t; R = 2048; C = 1024; bx = sub & 31; by = sub >> 5;
  }
  const int tx = threadIdx.x & 31, ty = threadIdx.x >> 5;
  const int c0 = bx * 32, r0 = by * 32;
#pragma unroll
  for (int k = 0; k < 4; ++k)
    t[ty + k * 8][tx] = in[(size_t)(r0 + ty + k * 8) * C + c0 + tx];
  __syncthreads();
#pragma unroll
  for (int k = 0; k < 4; ++k)
    out[(size_t)(c0 + ty + k * 8) * R + r0 + tx] = f2bf(t[tx][ty + k * 8]);
}

extern "C" void kernel_launch(void* const* d_in, const int* in_sizes, int n_in,
                              void* d_out, int out_size, void* d_ws, size_t ws_size,
                              hipStream_t stream)
{
  (void)in_sizes; (void)n_in; (void)out_size; (void)ws_size;  // needs ws_size >= 144MB
  const float* x   = (const float*)d_in[0];
  const float* msk = (const float*)d_in[1];
  const float* Wq  = (const float*)d_in[2];
  const float* Wk  = (const float*)d_in[3];
  const float* Wv  = (const float*)d_in[4];
  const float* Wc  = (const float*)d_in[5];
  const float* bc  = (const float*)d_in[6];
  const float* W1  = (const float*)d_in[7];
  const float* b1  = (const float*)d_in[8];
  const float* W2  = (const float*)d_in[9];
  const float* b2  = (const float*)d_in[10];
  const float* g1  = (const float*)d_in[11];
  const float* be1 = (const float*)d_in[12];
  const float* g2  = (const float*)d_in[13];
  const float* be2 = (const float*)d_in[14];
  float* out = (float*)d_out;
  char* ws = (char*)d_ws;
  const size_t MB = 1u << 20;
  unsigned short* xb    = (unsigned short*)(ws + 0 * MB);    // bf16 x, live to LN1
  unsigned short* wqkvt = (unsigned short*)(ws + 16 * MB);
  unsigned short* wct   = (unsigned short*)(ws + 22 * MB);
  unsigned short* w1t   = (unsigned short*)(ws + 24 * MB);
  unsigned short* w2t   = (unsigned short*)(ws + 28 * MB);
  unsigned short* qkv   = (unsigned short*)(ws + 32 * MB);   // 48MB, dead after attn
  unsigned short* vt    = (unsigned short*)(ws + 80 * MB);   // 16MB, dead after attn
  unsigned short* attnb = (unsigned short*)(ws + 96 * MB);   // 16MB, dead after proj
  unsigned short* h1b   = (unsigned short*)(ws + 128 * MB);  // 16MB, live to LN2
  unsigned short* prb   = (unsigned short*)(ws + 32 * MB);   // 32MB proj partials
  unsigned short* midb  = (unsigned short*)(ws + 32 * MB);   // 32MB FFN1 out (after LN1)
  unsigned short* pffb  = (unsigned short*)(ws + 64 * MB);   // 32MB FFN2 partials

  prep_kernel<<<16384, 256, 0, stream>>>(x, xb, Wq, Wk, Wv, Wc, W1, W2,
                                         wqkvt, wct, w1t, w2t);
  gemm8p<0, 1, 0><<<dim3(12, 32), 512, 0, stream>>>(xb, wqkvt, qkv, nullptr, vt,
                                                    8192, 3072, 1024);
  attn_kernel<<<dim3(32, 64), 256, 0, stream>>>(qkv, vt, msk, attnb);
  gemm8p<0, 0, 1><<<dim3(8, 32), 512, 0, stream>>>(attnb, wct, prb, nullptr, nullptr,
                                                   8192, 1024, 1024);
  ln_kernel<<<8192, 256, 0, stream>>>(prb, prb + (size_t)8192 * 1024,
                                      bc, xb, nullptr, h1b, g1, be1);
  gemm8p<1, 0, 0><<<dim3(8, 32), 512, 0, stream>>>(h1b, w1t, midb, b1, nullptr,
                                                   8192, 2048, 1024);
  gemm8p<0, 0, 1><<<dim3(8, 32), 512, 0, stream>>>(midb, w2t, pffb, nullptr, nullptr,
                                                   8192, 1024, 2048);
  ln_kernel<<<8192, 256, 0, stream>>>(pffb, pffb + (size_t)8192 * 1024,
                                      b2, h1b, out, nullptr, g2, be2);
}